// Round 1
// baseline (262.546 us; speedup 1.0000x reference)
//
#include <hip/hip_runtime.h>
#include <math.h>

#define HIDDEN 128
#define MAIN_BLOCKS 512
#define MAIN_THREADS 1024

// ---------------------------------------------------------------------------
// Kernel 1: q = [x ; X[start] ; X[prev]] @ Wq  (384x128), then qk = (Wk @ q)/sqrt(128)
// One block, 128 threads.
// ---------------------------------------------------------------------------
__global__ __launch_bounds__(128) void prep_kernel(
    const float* __restrict__ X, const float* __restrict__ x,
    const float* __restrict__ Wq, const float* __restrict__ Wk,
    const int* __restrict__ startp, const int* __restrict__ prevp,
    float* __restrict__ qk)
{
    __shared__ float fc[384];
    __shared__ float qv[128];
    const int t = threadIdx.x;
    const int start = startp[0];
    const int prev  = prevp[0];
    fc[t]       = x[t];
    fc[128 + t] = X[(size_t)start * HIDDEN + t];
    fc[256 + t] = X[(size_t)prev  * HIDDEN + t];
    __syncthreads();
    float acc = 0.f;
    #pragma unroll 4
    for (int m = 0; m < 384; ++m) acc += fc[m] * Wq[m * HIDDEN + t];
    qv[t] = acc;
    __syncthreads();
    float acc2 = 0.f;
    #pragma unroll 4
    for (int j = 0; j < HIDDEN; ++j) acc2 += Wk[t * HIDDEN + j] * qv[j];
    qk[t] = acc2 * 0.08838834764831845f;  // 1/sqrt(128)
}

// ---------------------------------------------------------------------------
// Kernel 2/3: additive mask = ones, zeros at visited (duplicate-safe scatter)
// ---------------------------------------------------------------------------
__global__ void fill_mask(float* __restrict__ mask, int n) {
    int i = blockIdx.x * blockDim.x + threadIdx.x;
    if (i < n) mask[i] = 1.0f;
}

__global__ void scatter_mask(float* __restrict__ mask, const int* __restrict__ visited, int nv) {
    int i = blockIdx.x * blockDim.x + threadIdx.x;
    if (i < nv) mask[visited[i]] = 0.0f;
}

// ---------------------------------------------------------------------------
// Kernel 4: streaming online softmax + weighted sum.
// One half-wave (32 lanes x float4 = 512B) per row; full wave reads 1 KiB
// contiguous. Per half-wave state: running max m, sum s, g[4]/lane.
// Block-level combine into per-block partials (Mb, Sb, Gb[128]).
// ---------------------------------------------------------------------------
__global__ __launch_bounds__(MAIN_THREADS) void main_kernel(
    const float* __restrict__ X, const float* __restrict__ mask,
    const float* __restrict__ qk,
    float* __restrict__ Mb, float* __restrict__ Sb, float* __restrict__ Gb,
    int n)
{
    const int tid  = threadIdx.x;
    const int lane = tid & 63;
    const int sub  = lane & 31;          // lane within half-wave
    const int half = (lane >> 5) & 1;
    const int wavesPerBlock = blockDim.x >> 6;             // 16
    const int gw  = blockIdx.x * wavesPerBlock + (tid >> 6);
    const int vhw = gw * 2 + half;                          // virtual half-wave id
    const int T   = gridDim.x * wavesPerBlock * 2;          // total half-waves

    const float4 qkv = *(const float4*)(qk + (sub << 2));

    float m = -INFINITY, s = 0.f;
    float g0 = 0.f, g1 = 0.f, g2 = 0.f, g3 = 0.f;

    for (int r = vhw; r < n; r += T) {
        const float4 xv = *(const float4*)(X + (size_t)r * HIDDEN + (sub << 2));
        float p = xv.x * qkv.x + xv.y * qkv.y + xv.z * qkv.z + xv.w * qkv.w;
        // butterfly reduce within the 32-lane half (xor <=16 never crosses bit 5)
        #pragma unroll
        for (int off = 16; off >= 1; off >>= 1)
            p += __shfl_xor(p, off, 64);
        const float u = p + mask[r];
        const float mn    = fmaxf(m, u);
        const float scale = __expf(m - mn);   // exp(-inf)=0 on first iter
        const float w     = __expf(u - mn);
        s  = s  * scale + w;
        g0 = g0 * scale + w * xv.x;
        g1 = g1 * scale + w * xv.y;
        g2 = g2 * scale + w * xv.z;
        g3 = g3 * scale + w * xv.w;
        m  = mn;
    }

    // ---- block combine: 32 half-waves -> 1 partial ----
    __shared__ float m_arr[32];
    __shared__ float s_arr[32];
    __shared__ float g_all[32 * HIDDEN];   // 16 KiB
    const int hw = tid >> 5;               // half-wave index in block, 0..31
    *(float4*)(&g_all[hw * HIDDEN + (sub << 2)]) = make_float4(g0, g1, g2, g3);
    if (sub == 0) { m_arr[hw] = m; s_arr[hw] = s; }
    __syncthreads();

    float mb = m_arr[0];
    #pragma unroll
    for (int h = 1; h < 32; ++h) mb = fmaxf(mb, m_arr[h]);

    if (tid < HIDDEN) {
        float G = 0.f;
        #pragma unroll 4
        for (int h = 0; h < 32; ++h)
            G += g_all[h * HIDDEN + tid] * __expf(m_arr[h] - mb);
        Gb[blockIdx.x * HIDDEN + tid] = G;
    } else if (tid == HIDDEN) {
        float S = 0.f;
        #pragma unroll
        for (int h = 0; h < 32; ++h) S += s_arr[h] * __expf(m_arr[h] - mb);
        Sb[blockIdx.x] = S;
        Mb[blockIdx.x] = mb;
    }
}

// ---------------------------------------------------------------------------
// Kernel 5: merge block partials -> softmax-weighted G, then h=G@Wv, out=h@Wo.
// One block, 256 threads. B = MAIN_BLOCKS partials.
// ---------------------------------------------------------------------------
__global__ __launch_bounds__(256) void finish_kernel(
    const float* __restrict__ Mb, const float* __restrict__ Sb,
    const float* __restrict__ Gb,
    const float* __restrict__ Wv, const float* __restrict__ Wo,
    float* __restrict__ out, int B)
{
    __shared__ float red[256];
    __shared__ float e[MAIN_BLOCKS];
    __shared__ float pvec[HIDDEN];
    __shared__ float hvec[HIDDEN];
    const int t = threadIdx.x;

    // global max
    float lm = -INFINITY;
    for (int b = t; b < B; b += 256) lm = fmaxf(lm, Mb[b]);
    red[t] = lm; __syncthreads();
    for (int st = 128; st >= 1; st >>= 1) {
        if (t < st) red[t] = fmaxf(red[t], red[t + st]);
        __syncthreads();
    }
    const float M = red[0];
    __syncthreads();

    // per-block scale factors + global sum
    float ls = 0.f;
    for (int b = t; b < B; b += 256) {
        const float eb = expf(Mb[b] - M);
        e[b] = eb;
        ls += Sb[b] * eb;
    }
    red[t] = ls; __syncthreads();
    for (int st = 128; st >= 1; st >>= 1) {
        if (t < st) red[t] += red[t + st];
        __syncthreads();
    }
    const float S = red[0];
    __syncthreads();

    if (t < HIDDEN) {
        float G = 0.f;
        for (int b = 0; b < B; ++b) G += Gb[b * HIDDEN + t] * e[b];
        pvec[t] = G / S;
    }
    __syncthreads();
    if (t < HIDDEN) {
        float h = 0.f;
        #pragma unroll 4
        for (int mm = 0; mm < HIDDEN; ++mm) h += pvec[mm] * Wv[mm * HIDDEN + t];
        hvec[t] = h;
    }
    __syncthreads();
    if (t < HIDDEN) {
        float o = 0.f;
        #pragma unroll 4
        for (int mm = 0; mm < HIDDEN; ++mm) o += hvec[mm] * Wo[mm * HIDDEN + t];
        out[t] = o;
    }
}

// ---------------------------------------------------------------------------
extern "C" void kernel_launch(void* const* d_in, const int* in_sizes, int n_in,
                              void* d_out, int out_size, void* d_ws, size_t ws_size,
                              hipStream_t stream)
{
    const float* X       = (const float*)d_in[0];
    const float* x       = (const float*)d_in[1];
    const float* Wq      = (const float*)d_in[2];
    const float* Wk      = (const float*)d_in[3];
    const float* Wv      = (const float*)d_in[4];
    const float* Wo      = (const float*)d_in[5];
    const int*   visited = (const int*)d_in[6];
    const int*   startp  = (const int*)d_in[7];
    const int*   prevp   = (const int*)d_in[8];

    const int n  = in_sizes[0] / HIDDEN;   // 200000
    const int nv = in_sizes[6];            // 1024

    // workspace layout (floats)
    float* ws   = (float*)d_ws;
    float* qk   = ws;                                   // 128
    float* Mb   = ws + 128;                             // MAIN_BLOCKS
    float* Sb   = Mb + MAIN_BLOCKS;                     // MAIN_BLOCKS
    float* Gb   = Sb + MAIN_BLOCKS;                     // MAIN_BLOCKS*128
    float* mask = Gb + MAIN_BLOCKS * HIDDEN;            // n

    prep_kernel<<<1, 128, 0, stream>>>(X, x, Wq, Wk, startp, prevp, qk);
    fill_mask<<<(n + 255) / 256, 256, 0, stream>>>(mask, n);
    scatter_mask<<<(nv + 255) / 256, 256, 0, stream>>>(mask, visited, nv);
    main_kernel<<<MAIN_BLOCKS, MAIN_THREADS, 0, stream>>>(X, mask, qk, Mb, Sb, Gb, n);
    finish_kernel<<<1, 256, 0, stream>>>(Mb, Sb, Gb, Wv, Wo, (float*)d_out, MAIN_BLOCKS);
}

// Round 2
// 187.359 us; speedup vs baseline: 1.4013x; 1.4013x over previous
//
#include <hip/hip_runtime.h>
#include <math.h>

#define HIDDEN 128
#define MAIN_BLOCKS 512
#define MAIN_THREADS 1024
#define MAX_BMAP_WORDS 6272   // 200704 bits >= 200000 nodes

// ---------------------------------------------------------------------------
// Kernel 1: q = [x ; X[start] ; X[prev]] @ Wq (384x128), qk = (Wk @ q)/sqrt(128)
// One block, 512 threads (8 waves): split-K + LDS reduce for q;
// half-wave-per-row coalesced float4 reads for the Wk GEMV.
// ---------------------------------------------------------------------------
__global__ __launch_bounds__(512) void prep_kernel(
    const float* __restrict__ X, const float* __restrict__ x,
    const float* __restrict__ Wq, const float* __restrict__ Wk,
    const int* __restrict__ startp, const int* __restrict__ prevp,
    float* __restrict__ qk)
{
    __shared__ float fc[384];
    __shared__ float qpart[4][HIDDEN];
    __shared__ float qv[HIDDEN];
    const int t   = threadIdx.x;
    const int col = t & (HIDDEN - 1);
    const int seg = t >> 7;               // 0..3

    if (t < 128)       fc[t]       = x[t];
    else if (t < 256)  fc[t]       = X[(size_t)startp[0] * HIDDEN + (t - 128)];
    else if (t < 384)  fc[t]       = X[(size_t)prevp[0]  * HIDDEN + (t - 256)];
    __syncthreads();

    // q[col] = sum_m fc[m] * Wq[m*128+col]; split m into 4 segments of 96
    float acc = 0.f;
    const int m0 = seg * 96;
    #pragma unroll 8
    for (int m = 0; m < 96; ++m)
        acc += fc[m0 + m] * Wq[(size_t)(m0 + m) * HIDDEN + col];
    qpart[seg][col] = acc;
    __syncthreads();
    if (t < HIDDEN)
        qv[t] = qpart[0][t] + qpart[1][t] + qpart[2][t] + qpart[3][t];
    __syncthreads();

    // qk[row] = (Wk[row,:] . qv) / sqrt(128); half-wave per row, coalesced
    const int hw  = t >> 5;               // 0..15
    const int sub = t & 31;
    const float4 qv4 = *(const float4*)(&qv[sub << 2]);
    for (int row = hw; row < HIDDEN; row += 16) {
        const float4 wk4 = *(const float4*)(Wk + (size_t)row * HIDDEN + (sub << 2));
        float p = wk4.x * qv4.x + wk4.y * qv4.y + wk4.z * qv4.z + wk4.w * qv4.w;
        #pragma unroll
        for (int off = 16; off >= 1; off >>= 1)
            p += __shfl_xor(p, off, 64);
        if (sub == 0) qk[row] = p * 0.08838834764831845f;
    }
}

// ---------------------------------------------------------------------------
// Kernel 2: streaming online softmax + weighted sum over X (single pass).
// Visited mask kept as a per-block LDS bitmap (duplicate-safe via atomicOr).
// Half-wave (32 lanes x float4 = 512B) per row; wave reads 1 KiB contiguous.
// ---------------------------------------------------------------------------
__global__ __launch_bounds__(MAIN_THREADS) void main_kernel(
    const float* __restrict__ X, const int* __restrict__ visited, int nv,
    const float* __restrict__ qk,
    float* __restrict__ Mb, float* __restrict__ Sb, float* __restrict__ Gb,
    int n)
{
    __shared__ unsigned bmap[MAX_BMAP_WORDS];
    __shared__ float m_arr[32];
    __shared__ float s_arr[32];
    __shared__ float g_all[32 * HIDDEN];   // 16 KiB

    const int tid  = threadIdx.x;
    const int lane = tid & 63;
    const int sub  = lane & 31;
    const int half = (lane >> 5) & 1;
    const int wavesPerBlock = blockDim.x >> 6;             // 16
    const int gw  = blockIdx.x * wavesPerBlock + (tid >> 6);
    const int vhw = gw * 2 + half;
    const int T   = gridDim.x * wavesPerBlock * 2;

    // build visited bitmap in LDS
    const int nwords = (n + 31) >> 5;
    for (int w = tid; w < nwords; w += blockDim.x) bmap[w] = 0u;
    __syncthreads();
    for (int i = tid; i < nv; i += blockDim.x) {
        const int v = visited[i];
        atomicOr(&bmap[v >> 5], 1u << (v & 31));
    }
    __syncthreads();

    const float4 qkv = *(const float4*)(qk + (sub << 2));

    float m = -INFINITY, s = 0.f;
    float g0 = 0.f, g1 = 0.f, g2 = 0.f, g3 = 0.f;

    for (int r = vhw; r < n; r += T) {
        const float4 xv = *(const float4*)(X + (size_t)r * HIDDEN + (sub << 2));
        float p = xv.x * qkv.x + xv.y * qkv.y + xv.z * qkv.z + xv.w * qkv.w;
        #pragma unroll
        for (int off = 16; off >= 1; off >>= 1)
            p += __shfl_xor(p, off, 64);
        const float maskv = ((bmap[r >> 5] >> (r & 31)) & 1u) ? 0.f : 1.f;
        const float u = p + maskv;
        const float mn    = fmaxf(m, u);
        const float scale = __expf(m - mn);   // exp(-inf)=0 on first iter
        const float w     = __expf(u - mn);
        s  = s  * scale + w;
        g0 = g0 * scale + w * xv.x;
        g1 = g1 * scale + w * xv.y;
        g2 = g2 * scale + w * xv.z;
        g3 = g3 * scale + w * xv.w;
        m  = mn;
    }

    // ---- block combine: 32 half-waves -> 1 partial ----
    const int hw = tid >> 5;
    *(float4*)(&g_all[hw * HIDDEN + (sub << 2)]) = make_float4(g0, g1, g2, g3);
    if (sub == 0) { m_arr[hw] = m; s_arr[hw] = s; }
    __syncthreads();

    float mb = m_arr[0];
    #pragma unroll
    for (int h = 1; h < 32; ++h) mb = fmaxf(mb, m_arr[h]);

    if (tid < HIDDEN) {
        float G = 0.f;
        #pragma unroll 4
        for (int h = 0; h < 32; ++h)
            G += g_all[h * HIDDEN + tid] * __expf(m_arr[h] - mb);
        Gb[blockIdx.x * HIDDEN + tid] = G;
    } else if (tid == HIDDEN) {
        float S = 0.f;
        #pragma unroll
        for (int h = 0; h < 32; ++h) S += s_arr[h] * __expf(m_arr[h] - mb);
        Sb[blockIdx.x] = S;
        Mb[blockIdx.x] = mb;
    }
}

// ---------------------------------------------------------------------------
// Kernel 3: merge block partials -> pvec = softmax-weighted mean of X rows,
// then h = pvec@Wv, out = h@Wo. One block, 512 threads, split-B/split-m + LDS.
// ---------------------------------------------------------------------------
__global__ __launch_bounds__(512) void finish_kernel(
    const float* __restrict__ Mb, const float* __restrict__ Sb,
    const float* __restrict__ Gb,
    const float* __restrict__ Wv, const float* __restrict__ Wo,
    float* __restrict__ out, int B)
{
    __shared__ float red[512];
    __shared__ float e[MAIN_BLOCKS];
    __shared__ float part[4][HIDDEN];
    __shared__ float pvec[HIDDEN];
    __shared__ float hvec[HIDDEN];
    const int t   = threadIdx.x;
    const int col = t & (HIDDEN - 1);
    const int seg = t >> 7;               // 0..3

    // global max over B=512 block maxima (one per thread)
    const float mt = (t < B) ? Mb[t] : -INFINITY;
    red[t] = mt; __syncthreads();
    for (int st = 256; st >= 1; st >>= 1) {
        if (t < st) red[t] = fmaxf(red[t], red[t + st]);
        __syncthreads();
    }
    const float M = red[0];
    __syncthreads();

    // per-block scale + global softmax denominator
    float ls = 0.f;
    if (t < B) { const float eb = __expf(mt - M); e[t] = eb; ls = Sb[t] * eb; }
    red[t] = ls; __syncthreads();
    for (int st = 256; st >= 1; st >>= 1) {
        if (t < st) red[t] += red[t + st];
        __syncthreads();
    }
    const float S = red[0];
    __syncthreads();

    // G[col] = sum_b Gb[b,col]*e[b]; split b into 4 segments of B/4
    {
        float acc = 0.f;
        const int b0 = seg * (B >> 2);
        #pragma unroll 8
        for (int b = 0; b < (MAIN_BLOCKS >> 2); ++b)
            acc += Gb[(size_t)(b0 + b) * HIDDEN + col] * e[b0 + b];
        part[seg][col] = acc;
    }
    __syncthreads();
    if (t < HIDDEN)
        pvec[t] = (part[0][t] + part[1][t] + part[2][t] + part[3][t]) / S;
    __syncthreads();

    // h[col] = sum_m pvec[m]*Wv[m,col]; split m into 4 segments of 32
    {
        float acc = 0.f;
        const int m0 = seg * 32;
        #pragma unroll 8
        for (int m = 0; m < 32; ++m)
            acc += pvec[m0 + m] * Wv[(size_t)(m0 + m) * HIDDEN + col];
        part[seg][col] = acc;
    }
    __syncthreads();
    if (t < HIDDEN)
        hvec[t] = part[0][t] + part[1][t] + part[2][t] + part[3][t];
    __syncthreads();

    // out[col] = sum_m h[m]*Wo[m,col]
    {
        float acc = 0.f;
        const int m0 = seg * 32;
        #pragma unroll 8
        for (int m = 0; m < 32; ++m)
            acc += hvec[m0 + m] * Wo[(size_t)(m0 + m) * HIDDEN + col];
        part[seg][col] = acc;
    }
    __syncthreads();
    if (t < HIDDEN)
        out[t] = part[0][t] + part[1][t] + part[2][t] + part[3][t];
}

// ---------------------------------------------------------------------------
extern "C" void kernel_launch(void* const* d_in, const int* in_sizes, int n_in,
                              void* d_out, int out_size, void* d_ws, size_t ws_size,
                              hipStream_t stream)
{
    const float* X       = (const float*)d_in[0];
    const float* x       = (const float*)d_in[1];
    const float* Wq      = (const float*)d_in[2];
    const float* Wk      = (const float*)d_in[3];
    const float* Wv      = (const float*)d_in[4];
    const float* Wo      = (const float*)d_in[5];
    const int*   visited = (const int*)d_in[6];
    const int*   startp  = (const int*)d_in[7];
    const int*   prevp   = (const int*)d_in[8];

    const int n  = in_sizes[0] / HIDDEN;   // 200000
    const int nv = in_sizes[6];            // 1024

    float* ws = (float*)d_ws;
    float* qk = ws;                        // 128
    float* Mb = ws + 128;                  // MAIN_BLOCKS
    float* Sb = Mb + MAIN_BLOCKS;          // MAIN_BLOCKS
    float* Gb = Sb + MAIN_BLOCKS;          // MAIN_BLOCKS*128

    prep_kernel<<<1, 512, 0, stream>>>(X, x, Wq, Wk, startp, prevp, qk);
    main_kernel<<<MAIN_BLOCKS, MAIN_THREADS, 0, stream>>>(X, visited, nv, qk, Mb, Sb, Gb, n);
    finish_kernel<<<1, 512, 0, stream>>>(Mb, Sb, Gb, Wv, Wo, (float*)d_out, MAIN_BLOCKS);
}